// Round 14
// baseline (184.299 us; speedup 1.0000x reference)
//
#include <hip/hip_runtime.h>

#define NN 4096
#define HD 64
#define KNB 15
#define NE 32768
#define NM (NE + NN*KNB)   // 94208 edges total (with duplicates)
#define W64 (NN/64)        // 64 u64 words per bitmap row
#define RB 4               // output rows per block in final_kernel
#define MAXH 96            // ELL pitch: max slices per 64-col chunk
#define NCH (NN/64)        // 64 column chunks
#define TDP 65             // padded LDS stride for 64x64 weights (conflict-free)
#define QPC (MAXH/4)       // s-quads per column in vals

typedef unsigned long long u64;
typedef unsigned int u32;

// order-preserving float->uint map
__device__ __forceinline__ u32 fmapu(float f) {
  int i = __float_as_int(f);
  return (u32)(i ^ ((i >> 31) | 0x80000000));
}

__device__ __forceinline__ u64 shfl_xor_u64(u64 v, int off) {
  int lo = __shfl_xor((int)(v & 0xFFFFFFFFull), off, 64);
  int hi = __shfl_xor((int)(v >> 32), off, 64);
  return ((u64)(u32)hi << 32) | (u32)lo;
}

__device__ __forceinline__ float dot64(const float* __restrict__ a,
                                       const float* __restrict__ b) {
  const float4* a4 = (const float4*)a;
  const float4* b4 = (const float4*)b;
  float s = 0.f;
#pragma unroll
  for (int t = 0; t < 16; ++t) {
    float4 x = a4[t], y = b4[t];
    s = fmaf(x.x, y.x, s); s = fmaf(x.y, y.y, s);
    s = fmaf(x.z, y.z, s); s = fmaf(x.w, y.w, s);
  }
  return s;
}

__device__ __forceinline__ void edge_decode(int m, const int* __restrict__ ei,
                                            const int* __restrict__ knn_idx,
                                            int& s, int& d) {
  if (m < NE) { s = ei[m]; d = ei[NE + m]; }
  else { int mm = m - NE; s = mm / KNB; d = knn_idx[mm]; }
}

// ---------- KNN: block per node; per-wave top-15 extraction (no barriers) --
// Each wave extracts its own 15 smallest (shuffle-only); a single rank-
// select pass over the 60 candidates picks the global top-15. Exact: every
// global-top-15 element is within its wave's top-15; u64 keys are distinct.
__global__ __launch_bounds__(256) void knn_kernel(const float* __restrict__ pts,
                                                  int* __restrict__ knn_idx,
                                                  u64* __restrict__ bR,
                                                  u32* __restrict__ zero_base,
                                                  int zero_n) {
  // fold: zero denom (contiguous); one u32 per thread, blocks 0..15 active
  int zi = blockIdx.x * 256 + threadIdx.x;
  if (zi < zero_n) zero_base[zi] = 0u;

  __shared__ u64 wtop[4][KNB];   // per-wave ascending top-15
  __shared__ u64 s_mask[64];     // own bitmap row
  int i = blockIdx.x;
  int tid = threadIdx.x;
  int lane = tid & 63, wv = tid >> 6;
  float px = pts[i*3+0], py = pts[i*3+1], pz = pts[i*3+2];
  // match np: (x*x + y*y) + z*z, no fma contraction
  float sqi = __fadd_rn(__fadd_rn(__fmul_rn(px,px), __fmul_rn(py,py)), __fmul_rn(pz,pz));
  u64 lk[16];
#pragma unroll
  for (int s = 0; s < 16; ++s) {
    int j = s*256 + tid;
    float x = pts[j*3+0], y = pts[j*3+1], z = pts[j*3+2];
    float sqj = __fadd_rn(__fadd_rn(__fmul_rn(x,x), __fmul_rn(y,y)), __fmul_rn(z,z));
    // match BLAS fma chain: acc = x*xj; fma(y,..); fma(z,..)
    float dot = fmaf(pz, z, fmaf(py, y, __fmul_rn(px, x)));
    float d2 = __fadd_rn(__fsub_rn(sqi, __fmul_rn(2.0f, dot)), sqj);
    u32 key = (j == i) ? 0xFFFFFFFFu : fmapu(d2);   // finite d2 keys < 0xFFFFFFFF
    lk[s] = ((u64)key << 32) | (u32)j;
  }
  // local min of 16 (registers, static indices)
  u64 lmin = lk[0];
#pragma unroll
  for (int s = 1; s < 16; ++s) lmin = (lk[s] < lmin) ? lk[s] : lmin;

  for (int r = 0; r < KNB; ++r) {
    u64 v = lmin;
#pragma unroll
    for (int off = 32; off >= 1; off >>= 1) {
      u64 o = shfl_xor_u64(v, off);
      if (o < v) v = o;
    }
    if (lane == 0) wtop[wv][r] = v;
    int j = (int)(u32)(v & 0xFFFFFFFFull);
    int owner = j & 63, sid = j >> 8;   // j = s*256 + wv*64 + lane -> lane = j&63
    if (lane == owner) {   // only the owner lane's set changed
#pragma unroll
      for (int s2 = 0; s2 < 16; ++s2) if (s2 == sid) lk[s2] = ~0ull;
      lmin = lk[0];
#pragma unroll
      for (int s2 = 1; s2 < 16; ++s2) lmin = (lk[s2] < lmin) ? lk[s2] : lmin;
    }
  }
  if (tid < 64) s_mask[tid] = 0ull;
  __syncthreads();   // wtop complete + mask zeroed
  if (tid < 4*KNB) {  // 60 lanes: rank = #elements smaller (keys distinct)
    u64 x = wtop[tid / KNB][tid % KNB];
    int rank = 0;
#pragma unroll
    for (int w2 = 0; w2 < 4; ++w2)
#pragma unroll
      for (int r2 = 0; r2 < KNB; ++r2)
        rank += (wtop[w2][r2] < x) ? 1 : 0;
    if (rank < KNB) {
      int j = (int)(u32)(x & 0xFFFFFFFFull);
      knn_idx[i*KNB + rank] = j;
      atomicOr(&s_mask[j >> 6], 1ull << (j & 63));
    }
  }
  __syncthreads();
  if (tid < 64) bR[(size_t)i*W64 + tid] = s_mask[tid];
}

// ---------- OR the explicit ei edges into the row bitmap ----------
__global__ void bitmap_kernel(const int* __restrict__ ei, u64* __restrict__ bR) {
  int m = blockIdx.x * 256 + threadIdx.x;
  if (m >= NE) return;
  int s = ei[m], d = ei[NE + m];
  atomicOr(&bR[(size_t)s*W64 + (d >> 6)], 1ull << (d & 63));
}

// ---------- fused: bitmap-row decode (deg + ELL cols) -> theta max -> ------
// dev = relu(W_phi .) -> q,k.  8 waves/block, wave = node.
// theta-max: 4-deep pts-load batches (max reorder exact). GEMVs: 4-way ILP
// partial sums (16-deep FMA chains instead of 64).
__global__ __launch_bounds__(512) void theta_devqk_kernel(const float* __restrict__ pts,
    const u64* __restrict__ bR, int* __restrict__ deg, uint2* __restrict__ cvT,
    const float* __restrict__ Wt, const float* __restrict__ bt,
    const float* __restrict__ Wp, const float* __restrict__ bp,
    const float* __restrict__ Wq, const float* __restrict__ bq,
    const float* __restrict__ Wk, const float* __restrict__ bk,
    float* __restrict__ qv, float* __restrict__ kv) {
  __shared__ float Wps[HD*TDP], Wqs[HD*TDP], Wks[HD*TDP];  // 3 x 16.25KB
  __shared__ float mf[8][HD];
  __shared__ float dv[8][HD];
  __shared__ int colbuf[8][MAXH];                          // 3KB, rows 384B
  int tid = threadIdx.x;
  for (int m = tid; m < HD*HD; m += 512) {
    int row = m >> 6, col = m & 63;
    Wps[row*TDP + col] = Wp[m];
    Wqs[row*TDP + col] = Wq[m];
    Wks[row*TDP + col] = Wk[m];
  }
  int lane = tid & 63, sub = tid >> 6;
  int i = blockIdx.x * 8 + sub;
  // --- decode bitmap row i: lane = word index (coalesced) ---
  u64 word = bR[(size_t)i*W64 + lane];
  int cnt = __popcll(word);
  int x = cnt;
#pragma unroll
  for (int o = 1; o < 64; o <<= 1) {
    int v = __shfl_up(x, o, 64);
    if (lane >= o) x += v;
  }
  int rank = x - cnt;                 // exclusive prefix
  int degi = __shfl(x, 63, 64);       // total set bits
  if (lane == 63) deg[i] = x;
  int ci = i >> 6, il = i & 63;
  u32* colTx = (u32*)cvT;             // .x components at even u32 offsets
  int slot = rank;
  u64 wtmp = word;
  while (wtmp) {
    int b = __builtin_ctzll(wtmp); wtmp &= wtmp - 1;
    int col = lane*64 + b;
    colbuf[sub][slot] = col;
    colTx[(((size_t)(ci*MAXH + slot) << 6) + il) << 1] = (u32)col;
    ++slot;
  }
  __syncthreads();
  // --- theta max over neighbors, 4-deep (max reorder exact) ---
  float w0 = Wt[lane*3+0], w1 = Wt[lane*3+1], w2 = Wt[lane*3+2], bb = bt[lane];
  float px = pts[i*3+0], py = pts[i*3+1], pz = pts[i*3+2];
  float m = -INFINITY;
  int e = 0;
  for (; e + 4 <= degi; e += 4) {
    int4 d4 = *(const int4*)&colbuf[sub][e];
    float dx0 = __fsub_rn(pts[d4.x*3+0], px), dy0 = __fsub_rn(pts[d4.x*3+1], py),
          dz0 = __fsub_rn(pts[d4.x*3+2], pz);
    float dx1 = __fsub_rn(pts[d4.y*3+0], px), dy1 = __fsub_rn(pts[d4.y*3+1], py),
          dz1 = __fsub_rn(pts[d4.y*3+2], pz);
    float dx2 = __fsub_rn(pts[d4.z*3+0], px), dy2 = __fsub_rn(pts[d4.z*3+1], py),
          dz2 = __fsub_rn(pts[d4.z*3+2], pz);
    float dx3 = __fsub_rn(pts[d4.w*3+0], px), dy3 = __fsub_rn(pts[d4.w*3+1], py),
          dz3 = __fsub_rn(pts[d4.w*3+2], pz);
    float t0 = fmaf(dz0, w2, fmaf(dy0, w1, __fmul_rn(dx0, w0)));
    float t1 = fmaf(dz1, w2, fmaf(dy1, w1, __fmul_rn(dx1, w0)));
    float t2 = fmaf(dz2, w2, fmaf(dy2, w1, __fmul_rn(dx2, w0)));
    float t3 = fmaf(dz3, w2, fmaf(dy3, w1, __fmul_rn(dx3, w0)));
    float m01 = fmaxf(__fadd_rn(t0, bb), __fadd_rn(t1, bb));
    float m23 = fmaxf(__fadd_rn(t2, bb), __fadd_rn(t3, bb));
    m = fmaxf(m, fmaxf(m01, m23));
  }
  for (; e < degi; ++e) {
    int d = colbuf[sub][e];
    float dx = __fsub_rn(pts[d*3+0], px);
    float dy = __fsub_rn(pts[d*3+1], py);
    float dz = __fsub_rn(pts[d*3+2], pz);
    float t = fmaf(dz, w2, fmaf(dy, w1, __fmul_rn(dx, w0)));
    m = fmaxf(m, __fadd_rn(t, bb));
  }
  mf[sub][lane] = m;
  __syncthreads();
  // --- dev GEMV, 4-way ILP ---
  {
    float a0 = 0.f, a1 = 0.f, a2 = 0.f, a3 = 0.f;
#pragma unroll
    for (int t = 0; t < HD; t += 4) {
      a0 = fmaf(Wps[lane*TDP + t    ], mf[sub][t    ], a0);
      a1 = fmaf(Wps[lane*TDP + t + 1], mf[sub][t + 1], a1);
      a2 = fmaf(Wps[lane*TDP + t + 2], mf[sub][t + 2], a2);
      a3 = fmaf(Wps[lane*TDP + t + 3], mf[sub][t + 3], a3);
    }
    float dvv = ((a0 + a1) + (a2 + a3)) + bp[lane];
    dv[sub][lane] = dvv > 0.f ? dvv : 0.f;
  }
  __syncthreads();
  // --- q,k GEMVs, 4-way ILP each ---
  float q0 = 0.f, q1 = 0.f, q2 = 0.f, q3 = 0.f;
  float k0 = 0.f, k1 = 0.f, k2 = 0.f, k3 = 0.f;
#pragma unroll
  for (int t = 0; t < HD; t += 4) {
    float x0 = dv[sub][t], x1 = dv[sub][t+1], x2 = dv[sub][t+2], x3 = dv[sub][t+3];
    q0 = fmaf(Wqs[lane*TDP + t    ], x0, q0);
    q1 = fmaf(Wqs[lane*TDP + t + 1], x1, q1);
    q2 = fmaf(Wqs[lane*TDP + t + 2], x2, q2);
    q3 = fmaf(Wqs[lane*TDP + t + 3], x3, q3);
    k0 = fmaf(Wks[lane*TDP + t    ], x0, k0);
    k1 = fmaf(Wks[lane*TDP + t + 1], x1, k1);
    k2 = fmaf(Wks[lane*TDP + t + 2], x2, k2);
    k3 = fmaf(Wks[lane*TDP + t + 3], x3, k3);
  }
  qv[(size_t)i*HD + lane] = ((q0 + q1) + (q2 + q3)) + bq[lane];
  kv[(size_t)i*HD + lane] = ((k0 + k1) + (k2 + k3)) + bk[lane];
}

// ---------- fused denom (raw edges, thread-per-edge serial dot: proven) ----
// + UNNORMALIZED vals (ELL quads: kv[j] register-cached across 4 slots).
#define DENOM_BLKS ((NM + 255) / 256)
#define ELL_BLKS   (NCH * QPC * 64 / 256)
__global__ void vals_kernel(const int* __restrict__ ei, const int* __restrict__ knn_idx,
    const int* __restrict__ deg,
    const float* __restrict__ qv, const float* __restrict__ kv,
    float* __restrict__ denom, uint2* __restrict__ cvT) {
  if ((int)blockIdx.x < DENOM_BLKS) {
    // denom over ALL M raw edges (duplicates count)
    int m = blockIdx.x * 256 + threadIdx.x;
    if (m >= NM) return;
    int s, d; edge_decode(m, ei, knn_idx, s, d);
    float e = expf(dot64(qv + (size_t)d*HD, kv + (size_t)s*HD));
    atomicAdd(&denom[s], e);
  } else {
    int t = (blockIdx.x - DENOM_BLKS) * 256 + threadIdx.x;
    int cq = t >> 6, jl = t & 63;
    int c = cq / QPC, q = cq - c * QPC;
    int j = c * 64 + jl;
    int s0 = q * 4;
    int dj = deg[j];
    if (s0 >= dj) return;
    float4 kr[16];
    const float4* kp = (const float4*)(kv + (size_t)j*HD);
#pragma unroll
    for (int u = 0; u < 16; ++u) kr[u] = kp[u];
    int nb = dj - s0; if (nb > 4) nb = 4;
#pragma unroll 4
    for (int u = 0; u < nb; ++u) {
      size_t slot = ((size_t)(c*MAXH + s0 + u) << 6) + jl;
      u32 l = ((const u32*)cvT)[slot << 1];
      const float4* qp = (const float4*)(qv + (size_t)l*HD);
      float sc = 0.f;
#pragma unroll
      for (int v = 0; v < 16; ++v) {
        float4 xq = qp[v], yk = kr[v];
        sc = fmaf(xq.x, yk.x, sc); sc = fmaf(xq.y, yk.y, sc);
        sc = fmaf(xq.z, yk.z, sc); sc = fmaf(xq.w, yk.w, sc);
      }
      ((u32*)cvT)[(slot << 1) + 1] = __float_as_uint(expf(sc));
    }
  }
}

// ---------- A_s rows [i0,i0+4): Phase A scatter into packed float4 LDS, ----
// Phase B coalesced ELL gather, 4-deep batches (proven no-spill), divide
// by denom_i * denom_j at store.
__global__ __launch_bounds__(1024, 8) void final_kernel(
    const int* __restrict__ deg, const uint2* __restrict__ cvT,
    const float* __restrict__ denom, float* __restrict__ out) {
  __shared__ float4 T4[NN];   // 64KB packed T~[l][0..3]
  int tid = threadIdx.x;
  int i0 = blockIdx.x * RB;
  float4 z4 = make_float4(0.f, 0.f, 0.f, 0.f);
  for (int t = tid; t < NN; t += 1024) T4[t] = z4;
  __syncthreads();
  int w = tid >> 6, lane = tid & 63;
  float* Tf = (float*)T4;
  const u32* colTx = (const u32*)cvT;
  // Phase A: 4 waves per output row r; T~_r[l] += e~[i0+r,k] for l in out(k)
  {
    int r = w & (RB - 1);
    int i = i0 + r;
    int ci = i >> 6, il = i & 63;
    int degi = deg[i];
    for (int idx = (w >> 2); idx < degi; idx += RB) {
      uint2 e = cvT[((size_t)(ci*MAXH + idx) << 6) + il];   // uniform
      int k = (int)e.x; float wv = __uint_as_float(e.y);
      int ck = k >> 6, kl = k & 63;
      int degk = deg[k];
      for (int t = lane; t < degk; t += 64) {
        u32 l = colTx[(((size_t)(ck*MAXH + t) << 6) + kl) << 1];
        atomicAdd(&Tf[(int)l * 4 + r], wv);
      }
    }
  }
  __syncthreads();
  // Phase B: thread owns cols {tid + g*1024}; 4-deep batches give 4
  // independent load->ds_read->fma chains in flight.
  float acc[4][RB];
#pragma unroll
  for (int g = 0; g < 4; ++g)
#pragma unroll
    for (int r = 0; r < RB; ++r) acc[g][r] = 0.f;
#pragma unroll
  for (int g = 0; g < 4; ++g) {
    int j = tid + g * 1024;
    int c = j >> 6;                 // wave-uniform chunk
    int dj = deg[j];
    const uint2* p = cvT + ((size_t)(c*MAXH) << 6) + (j & 63);
    int s = 0;
    for (; s + 4 <= dj; s += 4) {
      uint2 e0 = p[(size_t)(s+0) << 6];
      uint2 e1 = p[(size_t)(s+1) << 6];
      uint2 e2 = p[(size_t)(s+2) << 6];
      uint2 e3 = p[(size_t)(s+3) << 6];
      float4 t0 = T4[(int)e0.x];
      float4 t1 = T4[(int)e1.x];
      float4 t2 = T4[(int)e2.x];
      float4 t3 = T4[(int)e3.x];
      float v0 = __uint_as_float(e0.y), v1 = __uint_as_float(e1.y);
      float v2 = __uint_as_float(e2.y), v3 = __uint_as_float(e3.y);
      acc[g][0] = fmaf(v0, t0.x, acc[g][0]); acc[g][1] = fmaf(v0, t0.y, acc[g][1]);
      acc[g][2] = fmaf(v0, t0.z, acc[g][2]); acc[g][3] = fmaf(v0, t0.w, acc[g][3]);
      acc[g][0] = fmaf(v1, t1.x, acc[g][0]); acc[g][1] = fmaf(v1, t1.y, acc[g][1]);
      acc[g][2] = fmaf(v1, t1.z, acc[g][2]); acc[g][3] = fmaf(v1, t1.w, acc[g][3]);
      acc[g][0] = fmaf(v2, t2.x, acc[g][0]); acc[g][1] = fmaf(v2, t2.y, acc[g][1]);
      acc[g][2] = fmaf(v2, t2.z, acc[g][2]); acc[g][3] = fmaf(v2, t2.w, acc[g][3]);
      acc[g][0] = fmaf(v3, t3.x, acc[g][0]); acc[g][1] = fmaf(v3, t3.y, acc[g][1]);
      acc[g][2] = fmaf(v3, t3.z, acc[g][2]); acc[g][3] = fmaf(v3, t3.w, acc[g][3]);
    }
    for (; s < dj; ++s) {
      uint2 e = p[(size_t)s << 6];
      float v = __uint_as_float(e.y);
      float4 tv = T4[(int)e.x];
      acc[g][0] = fmaf(v, tv.x, acc[g][0]);
      acc[g][1] = fmaf(v, tv.y, acc[g][1]);
      acc[g][2] = fmaf(v, tv.z, acc[g][2]);
      acc[g][3] = fmaf(v, tv.w, acc[g][3]);
    }
  }
  float rden[RB];
#pragma unroll
  for (int r = 0; r < RB; ++r) rden[r] = 1.0f / denom[i0 + r];
#pragma unroll
  for (int g = 0; g < 4; ++g) {
    int j = tid + g * 1024;
    float dj_den = denom[j];
#pragma unroll
    for (int r = 0; r < RB; ++r)
      out[(size_t)(i0 + r) * NN + j] = acc[g][r] * rden[r] / dj_den;
  }
}

extern "C" void kernel_launch(void* const* d_in, const int* in_sizes, int n_in,
                              void* d_out, int out_size, void* d_ws, size_t ws_size,
                              hipStream_t stream) {
  (void)in_sizes; (void)n_in; (void)out_size;
  const float* pts = (const float*)d_in[0];
  // d_in[1] = features: unused by the reference
  const int* ei = (const int*)d_in[2];
  const float* Wt = (const float*)d_in[3];
  const float* bt = (const float*)d_in[4];
  const float* Wp = (const float*)d_in[5];
  const float* bp = (const float*)d_in[6];
  const float* Wq = (const float*)d_in[7];
  const float* bq = (const float*)d_in[8];
  const float* Wk = (const float*)d_in[9];
  const float* bk = (const float*)d_in[10];
  float* out = (float*)d_out;

  char* w = (char*)d_ws;
  u64* bR = (u64*)w;        w += (size_t)NN*W64*8;       // 2MB (written by knn)
  float* denom = (float*)w; w += (size_t)NN*4;           // 16KB (zeroed via fold)
  float* qv = (float*)w;    w += (size_t)NN*HD*4;        // 1MB
  float* kv = (float*)w;    w += (size_t)NN*HD*4;        // 1MB
  int* knn_idx = (int*)w;   w += (size_t)NN*KNB*4;
  int* deg = (int*)w;       w += (size_t)NN*4;
  uint2* cvT = (uint2*)w;   w += (size_t)NCH*MAXH*64*8;  // 3MB (padding never read)
  if ((size_t)(w - (char*)d_ws) > ws_size) return;  // insufficient scratch

  hipLaunchKernelGGL(knn_kernel, dim3(NN), dim3(256), 0, stream,
                     pts, knn_idx, bR, (u32*)denom, NN);
  hipLaunchKernelGGL(bitmap_kernel, dim3((NE+255)/256), dim3(256), 0, stream,
                     ei, bR);
  hipLaunchKernelGGL(theta_devqk_kernel, dim3(NN/8), dim3(512), 0, stream,
                     pts, bR, deg, cvT, Wt, bt, Wp, bp, Wq, bq, Wk, bk, qv, kv);
  hipLaunchKernelGGL(vals_kernel, dim3(DENOM_BLKS + ELL_BLKS), dim3(256), 0, stream,
                     ei, knn_idx, deg, qv, kv, denom, cvT);
  hipLaunchKernelGGL(final_kernel, dim3(NN/RB), dim3(1024), 0, stream,
                     deg, cvT, denom, out);
}

// Round 15
// 172.786 us; speedup vs baseline: 1.0666x; 1.0666x over previous
//
#include <hip/hip_runtime.h>

#define NN 4096
#define HD 64
#define KNB 15
#define NE 32768
#define NM (NE + NN*KNB)   // 94208 edges total (with duplicates)
#define W64 (NN/64)        // 64 u64 words per bitmap row
#define RB 4               // output rows per block in final_kernel
#define MAXH 96            // ELL pitch: max slices per 64-col chunk
#define NCH (NN/64)        // 64 column chunks
#define TDP 65             // padded LDS stride for 64x64 weights (conflict-free)
#define QPC (MAXH/4)       // s-quads per column in vals

typedef unsigned long long u64;
typedef unsigned int u32;

// order-preserving float->uint map
__device__ __forceinline__ u32 fmapu(float f) {
  int i = __float_as_int(f);
  return (u32)(i ^ ((i >> 31) | 0x80000000));
}

__device__ __forceinline__ u64 shfl_xor_u64(u64 v, int off) {
  int lo = __shfl_xor((int)(v & 0xFFFFFFFFull), off, 64);
  int hi = __shfl_xor((int)(v >> 32), off, 64);
  return ((u64)(u32)hi << 32) | (u32)lo;
}

__device__ __forceinline__ float dot64(const float* __restrict__ a,
                                       const float* __restrict__ b) {
  const float4* a4 = (const float4*)a;
  const float4* b4 = (const float4*)b;
  float s = 0.f;
#pragma unroll
  for (int t = 0; t < 16; ++t) {
    float4 x = a4[t], y = b4[t];
    s = fmaf(x.x, y.x, s); s = fmaf(x.y, y.y, s);
    s = fmaf(x.z, y.z, s); s = fmaf(x.w, y.w, s);
  }
  return s;
}

__device__ __forceinline__ void edge_decode(int m, const int* __restrict__ ei,
                                            const int* __restrict__ knn_idx,
                                            int& s, int& d) {
  if (m < NE) { s = ei[m]; d = ei[NE + m]; }
  else { int mm = m - NE; s = mm / KNB; d = knn_idx[mm]; }
}

// ---------- KNN: block per node; iterative top-15 extraction ---------------
// Incremental lmin: only the owner lane's candidate set changes per round,
// so only it recomputes its register min (1 active lane, 1 of 4 waves).
__global__ __launch_bounds__(256) void knn_kernel(const float* __restrict__ pts,
                                                  int* __restrict__ knn_idx,
                                                  u64* __restrict__ bR,
                                                  u32* __restrict__ zero_base,
                                                  int zero_n) {
  // fold: zero denom (contiguous); one u32 per thread, blocks 0..15 active
  int zi = blockIdx.x * 256 + threadIdx.x;
  if (zi < zero_n) zero_base[zi] = 0u;

  __shared__ u64 sm[KNB][4];     // per-round wave minima
  __shared__ u64 s_mask[64];     // own bitmap row
  __shared__ int s_j[KNB];       // selected neighbor ids
  int i = blockIdx.x;
  int tid = threadIdx.x;
  int lane = tid & 63, wv = tid >> 6;
  float px = pts[i*3+0], py = pts[i*3+1], pz = pts[i*3+2];
  // match np: (x*x + y*y) + z*z, no fma contraction
  float sqi = __fadd_rn(__fadd_rn(__fmul_rn(px,px), __fmul_rn(py,py)), __fmul_rn(pz,pz));
  u64 lk[16];
#pragma unroll
  for (int s = 0; s < 16; ++s) {
    int j = s*256 + tid;
    float x = pts[j*3+0], y = pts[j*3+1], z = pts[j*3+2];
    float sqj = __fadd_rn(__fadd_rn(__fmul_rn(x,x), __fmul_rn(y,y)), __fmul_rn(z,z));
    // match BLAS fma chain: acc = x*xj; fma(y,..); fma(z,..)
    float dot = fmaf(pz, z, fmaf(py, y, __fmul_rn(px, x)));
    float d2 = __fadd_rn(__fsub_rn(sqi, __fmul_rn(2.0f, dot)), sqj);
    u32 key = (j == i) ? 0xFFFFFFFFu : fmapu(d2);   // finite d2 keys < 0xFFFFFFFF
    lk[s] = ((u64)key << 32) | (u32)j;
  }
  // local min of 16 (registers, static indices)
  u64 lmin = lk[0];
#pragma unroll
  for (int s = 1; s < 16; ++s) lmin = (lk[s] < lmin) ? lk[s] : lmin;

  for (int r = 0; r < KNB; ++r) {
    u64 v = lmin;
#pragma unroll
    for (int off = 32; off >= 1; off >>= 1) {
      u64 o = shfl_xor_u64(v, off);
      if (o < v) v = o;
    }
    if (lane == 0) sm[r][wv] = v;
    __syncthreads();
    u64 bm = sm[r][0];
    if (sm[r][1] < bm) bm = sm[r][1];
    if (sm[r][2] < bm) bm = sm[r][2];
    if (sm[r][3] < bm) bm = sm[r][3];
    int j = (int)(u32)(bm & 0xFFFFFFFFull);
    if (tid == 0) { knn_idx[i*KNB + r] = j; s_j[r] = j; }
    int owner = j & 255, sid = j >> 8;
    if (tid == owner) {        // only the owner's set changed: recompute there
#pragma unroll
      for (int s2 = 0; s2 < 16; ++s2) if (s2 == sid) lk[s2] = ~0ull;
      lmin = lk[0];
#pragma unroll
      for (int s2 = 1; s2 < 16; ++s2) lmin = (lk[s2] < lmin) ? lk[s2] : lmin;
    }
  }
  // own bR row: mask of the 15 selected neighbors (plain stores; ei bits
  // are OR'd in by bitmap_kernel afterwards)
  if (tid < 64) s_mask[tid] = 0ull;
  __syncthreads();
  if (tid < KNB) {
    int j = s_j[tid];
    atomicOr(&s_mask[j >> 6], 1ull << (j & 63));
  }
  __syncthreads();
  if (tid < 64) bR[(size_t)i*W64 + tid] = s_mask[tid];
}

// ---------- OR the explicit ei edges into the row bitmap ----------
__global__ void bitmap_kernel(const int* __restrict__ ei, u64* __restrict__ bR) {
  int m = blockIdx.x * 256 + threadIdx.x;
  if (m >= NE) return;
  int s = ei[m], d = ei[NE + m];
  atomicOr(&bR[(size_t)s*W64 + (d >> 6)], 1ull << (d & 63));
}

// ---------- fused: bitmap-row decode (deg + ELL cols) -> theta max -> ------
// dev = relu(W_phi .) -> q,k.  8 waves/block, wave = node.
__global__ __launch_bounds__(512) void theta_devqk_kernel(const float* __restrict__ pts,
    const u64* __restrict__ bR, int* __restrict__ deg, uint2* __restrict__ cvT,
    const float* __restrict__ Wt, const float* __restrict__ bt,
    const float* __restrict__ Wp, const float* __restrict__ bp,
    const float* __restrict__ Wq, const float* __restrict__ bq,
    const float* __restrict__ Wk, const float* __restrict__ bk,
    float* __restrict__ qv, float* __restrict__ kv) {
  __shared__ float Wps[HD*TDP], Wqs[HD*TDP], Wks[HD*TDP];  // 3 x 16.25KB
  __shared__ float mf[8][HD];
  __shared__ float dv[8][HD];
  __shared__ int colbuf[8][MAXH];                          // 3KB
  int tid = threadIdx.x;
  for (int m = tid; m < HD*HD; m += 512) {
    int row = m >> 6, col = m & 63;
    Wps[row*TDP + col] = Wp[m];
    Wqs[row*TDP + col] = Wq[m];
    Wks[row*TDP + col] = Wk[m];
  }
  int lane = tid & 63, sub = tid >> 6;
  int i = blockIdx.x * 8 + sub;
  // --- decode bitmap row i: lane = word index (coalesced) ---
  u64 word = bR[(size_t)i*W64 + lane];
  int cnt = __popcll(word);
  int x = cnt;
#pragma unroll
  for (int o = 1; o < 64; o <<= 1) {
    int v = __shfl_up(x, o, 64);
    if (lane >= o) x += v;
  }
  int rank = x - cnt;                 // exclusive prefix
  int degi = __shfl(x, 63, 64);       // total set bits
  if (lane == 63) deg[i] = x;
  int ci = i >> 6, il = i & 63;
  u32* colTx = (u32*)cvT;             // .x components at even u32 offsets
  int slot = rank;
  u64 wtmp = word;
  while (wtmp) {
    int b = __builtin_ctzll(wtmp); wtmp &= wtmp - 1;
    int col = lane*64 + b;
    colbuf[sub][slot] = col;
    colTx[(((size_t)(ci*MAXH + slot) << 6) + il) << 1] = (u32)col;
    ++slot;
  }
  __syncthreads();
  // --- theta max over neighbors (cols ascending, same order as before) ---
  float w0 = Wt[lane*3+0], w1 = Wt[lane*3+1], w2 = Wt[lane*3+2], bb = bt[lane];
  float px = pts[i*3+0], py = pts[i*3+1], pz = pts[i*3+2];
  float m = -INFINITY;
  for (int e = 0; e < degi; ++e) {
    int d = colbuf[sub][e];
    float dx = __fsub_rn(pts[d*3+0], px);
    float dy = __fsub_rn(pts[d*3+1], py);
    float dz = __fsub_rn(pts[d*3+2], pz);
    float t = fmaf(dz, w2, fmaf(dy, w1, __fmul_rn(dx, w0)));
    m = fmaxf(m, __fadd_rn(t, bb));
  }
  mf[sub][lane] = m;
  __syncthreads();
  float a = 0.f;
#pragma unroll
  for (int t = 0; t < HD; ++t) a = fmaf(Wps[lane*TDP + t], mf[sub][t], a);
  float dvv = a + bp[lane];
  dv[sub][lane] = dvv > 0.f ? dvv : 0.f;
  __syncthreads();
  float aq = 0.f, ak = 0.f;
#pragma unroll
  for (int t = 0; t < HD; ++t) {
    float xv = dv[sub][t];
    aq = fmaf(Wqs[lane*TDP + t], xv, aq);
    ak = fmaf(Wks[lane*TDP + t], xv, ak);
  }
  qv[(size_t)i*HD + lane] = aq + bq[lane];
  kv[(size_t)i*HD + lane] = ak + bk[lane];
}

// ---------- fused denom (raw edges, thread-per-edge serial dot: proven) ----
// + UNNORMALIZED vals (ELL quads: kv[j] register-cached across 4 slots).
#define DENOM_BLKS ((NM + 255) / 256)
#define ELL_BLKS   (NCH * QPC * 64 / 256)
__global__ void vals_kernel(const int* __restrict__ ei, const int* __restrict__ knn_idx,
    const int* __restrict__ deg,
    const float* __restrict__ qv, const float* __restrict__ kv,
    float* __restrict__ denom, uint2* __restrict__ cvT) {
  if ((int)blockIdx.x < DENOM_BLKS) {
    // denom over ALL M raw edges (duplicates count)
    int m = blockIdx.x * 256 + threadIdx.x;
    if (m >= NM) return;
    int s, d; edge_decode(m, ei, knn_idx, s, d);
    float e = expf(dot64(qv + (size_t)d*HD, kv + (size_t)s*HD));
    atomicAdd(&denom[s], e);
  } else {
    int t = (blockIdx.x - DENOM_BLKS) * 256 + threadIdx.x;
    int cq = t >> 6, jl = t & 63;
    int c = cq / QPC, q = cq - c * QPC;
    int j = c * 64 + jl;
    int s0 = q * 4;
    int dj = deg[j];
    if (s0 >= dj) return;
    float4 kr[16];
    const float4* kp = (const float4*)(kv + (size_t)j*HD);
#pragma unroll
    for (int u = 0; u < 16; ++u) kr[u] = kp[u];
    int nb = dj - s0; if (nb > 4) nb = 4;
#pragma unroll 4
    for (int u = 0; u < nb; ++u) {
      size_t slot = ((size_t)(c*MAXH + s0 + u) << 6) + jl;
      u32 l = ((const u32*)cvT)[slot << 1];
      const float4* qp = (const float4*)(qv + (size_t)l*HD);
      float sc = 0.f;
#pragma unroll
      for (int v = 0; v < 16; ++v) {
        float4 xq = qp[v], yk = kr[v];
        sc = fmaf(xq.x, yk.x, sc); sc = fmaf(xq.y, yk.y, sc);
        sc = fmaf(xq.z, yk.z, sc); sc = fmaf(xq.w, yk.w, sc);
      }
      ((u32*)cvT)[(slot << 1) + 1] = __float_as_uint(expf(sc));
    }
  }
}

// ---------- A_s rows [i0,i0+4): Phase A scatter into packed float4 LDS, ----
// Phase B coalesced ELL gather, 4-deep batches (proven no-spill), divide
// by denom_i * denom_j at store.
__global__ __launch_bounds__(1024, 8) void final_kernel(
    const int* __restrict__ deg, const uint2* __restrict__ cvT,
    const float* __restrict__ denom, float* __restrict__ out) {
  __shared__ float4 T4[NN];   // 64KB packed T~[l][0..3]
  int tid = threadIdx.x;
  int i0 = blockIdx.x * RB;
  float4 z4 = make_float4(0.f, 0.f, 0.f, 0.f);
  for (int t = tid; t < NN; t += 1024) T4[t] = z4;
  __syncthreads();
  int w = tid >> 6, lane = tid & 63;
  float* Tf = (float*)T4;
  const u32* colTx = (const u32*)cvT;
  // Phase A: 4 waves per output row r; T~_r[l] += e~[i0+r,k] for l in out(k)
  {
    int r = w & (RB - 1);
    int i = i0 + r;
    int ci = i >> 6, il = i & 63;
    int degi = deg[i];
    for (int idx = (w >> 2); idx < degi; idx += RB) {
      uint2 e = cvT[((size_t)(ci*MAXH + idx) << 6) + il];   // uniform
      int k = (int)e.x; float wv = __uint_as_float(e.y);
      int ck = k >> 6, kl = k & 63;
      int degk = deg[k];
      for (int t = lane; t < degk; t += 64) {
        u32 l = colTx[(((size_t)(ck*MAXH + t) << 6) + kl) << 1];
        atomicAdd(&Tf[(int)l * 4 + r], wv);
      }
    }
  }
  __syncthreads();
  // Phase B: thread owns cols {tid + g*1024}; 4-deep batches give 4
  // independent load->ds_read->fma chains in flight.
  float acc[4][RB];
#pragma unroll
  for (int g = 0; g < 4; ++g)
#pragma unroll
    for (int r = 0; r < RB; ++r) acc[g][r] = 0.f;
#pragma unroll
  for (int g = 0; g < 4; ++g) {
    int j = tid + g * 1024;
    int c = j >> 6;                 // wave-uniform chunk
    int dj = deg[j];
    const uint2* p = cvT + ((size_t)(c*MAXH) << 6) + (j & 63);
    int s = 0;
    for (; s + 4 <= dj; s += 4) {
      uint2 e0 = p[(size_t)(s+0) << 6];
      uint2 e1 = p[(size_t)(s+1) << 6];
      uint2 e2 = p[(size_t)(s+2) << 6];
      uint2 e3 = p[(size_t)(s+3) << 6];
      float4 t0 = T4[(int)e0.x];
      float4 t1 = T4[(int)e1.x];
      float4 t2 = T4[(int)e2.x];
      float4 t3 = T4[(int)e3.x];
      float v0 = __uint_as_float(e0.y), v1 = __uint_as_float(e1.y);
      float v2 = __uint_as_float(e2.y), v3 = __uint_as_float(e3.y);
      acc[g][0] = fmaf(v0, t0.x, acc[g][0]); acc[g][1] = fmaf(v0, t0.y, acc[g][1]);
      acc[g][2] = fmaf(v0, t0.z, acc[g][2]); acc[g][3] = fmaf(v0, t0.w, acc[g][3]);
      acc[g][0] = fmaf(v1, t1.x, acc[g][0]); acc[g][1] = fmaf(v1, t1.y, acc[g][1]);
      acc[g][2] = fmaf(v1, t1.z, acc[g][2]); acc[g][3] = fmaf(v1, t1.w, acc[g][3]);
      acc[g][0] = fmaf(v2, t2.x, acc[g][0]); acc[g][1] = fmaf(v2, t2.y, acc[g][1]);
      acc[g][2] = fmaf(v2, t2.z, acc[g][2]); acc[g][3] = fmaf(v2, t2.w, acc[g][3]);
      acc[g][0] = fmaf(v3, t3.x, acc[g][0]); acc[g][1] = fmaf(v3, t3.y, acc[g][1]);
      acc[g][2] = fmaf(v3, t3.z, acc[g][2]); acc[g][3] = fmaf(v3, t3.w, acc[g][3]);
    }
    for (; s < dj; ++s) {
      uint2 e = p[(size_t)s << 6];
      float v = __uint_as_float(e.y);
      float4 tv = T4[(int)e.x];
      acc[g][0] = fmaf(v, tv.x, acc[g][0]);
      acc[g][1] = fmaf(v, tv.y, acc[g][1]);
      acc[g][2] = fmaf(v, tv.z, acc[g][2]);
      acc[g][3] = fmaf(v, tv.w, acc[g][3]);
    }
  }
  float rden[RB];
#pragma unroll
  for (int r = 0; r < RB; ++r) rden[r] = 1.0f / denom[i0 + r];
#pragma unroll
  for (int g = 0; g < 4; ++g) {
    int j = tid + g * 1024;
    float dj_den = denom[j];
#pragma unroll
    for (int r = 0; r < RB; ++r)
      out[(size_t)(i0 + r) * NN + j] = acc[g][r] * rden[r] / dj_den;
  }
}

extern "C" void kernel_launch(void* const* d_in, const int* in_sizes, int n_in,
                              void* d_out, int out_size, void* d_ws, size_t ws_size,
                              hipStream_t stream) {
  (void)in_sizes; (void)n_in; (void)out_size;
  const float* pts = (const float*)d_in[0];
  // d_in[1] = features: unused by the reference
  const int* ei = (const int*)d_in[2];
  const float* Wt = (const float*)d_in[3];
  const float* bt = (const float*)d_in[4];
  const float* Wp = (const float*)d_in[5];
  const float* bp = (const float*)d_in[6];
  const float* Wq = (const float*)d_in[7];
  const float* bq = (const float*)d_in[8];
  const float* Wk = (const float*)d_in[9];
  const float* bk = (const float*)d_in[10];
  float* out = (float*)d_out;

  char* w = (char*)d_ws;
  u64* bR = (u64*)w;        w += (size_t)NN*W64*8;       // 2MB (written by knn)
  float* denom = (float*)w; w += (size_t)NN*4;           // 16KB (zeroed via fold)
  float* qv = (float*)w;    w += (size_t)NN*HD*4;        // 1MB
  float* kv = (float*)w;    w += (size_t)NN*HD*4;        // 1MB
  int* knn_idx = (int*)w;   w += (size_t)NN*KNB*4;
  int* deg = (int*)w;       w += (size_t)NN*4;
  uint2* cvT = (uint2*)w;   w += (size_t)NCH*MAXH*64*8;  // 3MB (padding never read)
  if ((size_t)(w - (char*)d_ws) > ws_size) return;  // insufficient scratch

  hipLaunchKernelGGL(knn_kernel, dim3(NN), dim3(256), 0, stream,
                     pts, knn_idx, bR, (u32*)denom, NN);
  hipLaunchKernelGGL(bitmap_kernel, dim3((NE+255)/256), dim3(256), 0, stream,
                     ei, bR);
  hipLaunchKernelGGL(theta_devqk_kernel, dim3(NN/8), dim3(512), 0, stream,
                     pts, bR, deg, cvT, Wt, bt, Wp, bp, Wq, bq, Wk, bk, qv, kv);
  hipLaunchKernelGGL(vals_kernel, dim3(DENOM_BLKS + ELL_BLKS), dim3(256), 0, stream,
                     ei, knn_idx, deg, qv, kv, denom, cvT);
  hipLaunchKernelGGL(final_kernel, dim3(NN/RB), dim3(1024), 0, stream,
                     deg, cvT, denom, out);
}